// Round 15
// baseline (289.669 us; speedup 1.0000x reference)
//
#include <hip/hip_runtime.h>
#include <hip/hip_bf16.h>
#include <hip/hip_cooperative_groups.h>

namespace cg = cooperative_groups;

#define DIMF 512
#define NHEAD 8
#define DHEAD 64
#define BATCH 2
#define SEQN 2048
#define SEQM 2048
#define FPS 40        // padded LDS row stride (u16): 32 data + 8 pad -> 2-way banks
#define QSCALE 0.18033688011112042f   // 0.125 * log2(e)

typedef unsigned short u16;
typedef __attribute__((ext_vector_type(8))) short bf16x8;
typedef __attribute__((ext_vector_type(4))) float f32x4;

static __device__ __forceinline__ u16 f2bf(float f) {
    unsigned u = __float_as_uint(f);
    u += 0x7FFF + ((u >> 16) & 1);      // RNE
    return (u16)(u >> 16);
}
static __device__ __forceinline__ u16 f2bf_fast(float f) {
    return (u16)((__float_as_uint(f) + 0x8000u) >> 16);
}
static __device__ __forceinline__ ushort4 cvt4(float4 v) {
    return make_ushort4(f2bf(v.x), f2bf(v.y), f2bf(v.z), f2bf(v.w));
}
// mask ints -> bf16 {0,1} x8 fragment
static __device__ __forceinline__ bf16x8 mask8(const int* p) {
    int4 a = *(const int4*)p;
    int4 b = *(const int4*)(p + 4);
    union { u16 u[8]; bf16x8 v; } r;
    r.u[0] = a.x ? 0x3F80 : 0; r.u[1] = a.y ? 0x3F80 : 0;
    r.u[2] = a.z ? 0x3F80 : 0; r.u[3] = a.w ? 0x3F80 : 0;
    r.u[4] = b.x ? 0x3F80 : 0; r.u[5] = b.y ? 0x3F80 : 0;
    r.u[6] = b.z ? 0x3F80 : 0; r.u[7] = b.w ? 0x3F80 : 0;
    return r.v;
}

static __device__ __forceinline__
void load16(const u16* g, u16* l) {
    __builtin_amdgcn_global_load_lds(
        (const __attribute__((address_space(1))) void*)g,
        (__attribute__((address_space(3))) void*)l,
        16, 0, 0);
}

#define ASZ (64 * FPS)
#define BSZ (128 * FPS)

// ---------------------------------------------------------------------------
// GEMM tile (R14's measured-best): double-buffered, one barrier per K-step.
// A from fp32 (fused cvt) or bf16; W bf16. 64x128 tile, 4 waves, wave 32x64.
// mode 0: q bf16 (xQSCALE)  1: k bf16  2: V^T bf16 masked+transposed  3: fp32
// ---------------------------------------------------------------------------
__device__ __forceinline__
void gemm_tile(u16* __restrict__ SH,
               const float* __restrict__ Xf, const u16* __restrict__ Xb,
               const u16* __restrict__ W, const float* __restrict__ bias,
               const int* __restrict__ msk, void* __restrict__ Out, int mode,
               int bx, int by)
{
    const int tid  = threadIdx.x;
    const int wave = tid >> 6;
    const int lane = tid & 63;
    const int l15  = lane & 15;
    const int quad = lane >> 4;
    const int wm = wave & 1, wn = wave >> 1;
    const int r0 = bx * 64, c0 = by * 128;

    f32x4 acc[2][4] = {};

    const int br = tid >> 2, boct = tid & 3;        // B/bf16-A: rows br, br+64
    const int ar = tid >> 3, aseg = tid & 7;        // A fp32: rows ar, ar+32

    bf16x8 rb0, rb1, rab;
    float4 ra0, ra1;

    auto loadg = [&](int k0) {
        rb0 = *(const bf16x8*)&W[(size_t)(c0 + br) * DIMF + k0 + boct * 8];
        rb1 = *(const bf16x8*)&W[(size_t)(c0 + br + 64) * DIMF + k0 + boct * 8];
        if (Xf) {
            ra0 = *(const float4*)&Xf[(size_t)(r0 + ar) * DIMF + k0 + aseg * 4];
            ra1 = *(const float4*)&Xf[(size_t)(r0 + ar + 32) * DIMF + k0 + aseg * 4];
        } else {
            rab = *(const bf16x8*)&Xb[(size_t)(r0 + br) * DIMF + k0 + boct * 8];
        }
    };
    auto stage = [&](int buf) {
        u16* As = SH + buf * ASZ;
        u16* Bs = SH + 2 * ASZ + buf * BSZ;
        if (Xf) {
            *(ushort4*)&As[ar * FPS + aseg * 4] = cvt4(ra0);
            *(ushort4*)&As[(ar + 32) * FPS + aseg * 4] = cvt4(ra1);
        } else {
            *(bf16x8*)&As[br * FPS + boct * 8] = rab;
        }
        *(bf16x8*)&Bs[br * FPS + boct * 8] = rb0;
        *(bf16x8*)&Bs[(br + 64) * FPS + boct * 8] = rb1;
    };

    loadg(0);
    stage(0);
    loadg(32);
    __syncthreads();

    const int NK = DIMF / 32;   // 16
    for (int kt = 0; kt < NK; ++kt) {
        const int cur = kt & 1;
        if (kt + 1 < NK) stage(cur ^ 1);
        if (kt + 2 < NK) loadg((kt + 2) * 32);
        const u16* As = SH + cur * ASZ;
        const u16* Bs = SH + 2 * ASZ + cur * BSZ;

        bf16x8 af[2], bf[4];
        #pragma unroll
        for (int mi = 0; mi < 2; ++mi)
            af[mi] = *(const bf16x8*)&As[(wm * 32 + mi * 16 + l15) * FPS + quad * 8];
        #pragma unroll
        for (int ni = 0; ni < 4; ++ni)
            bf[ni] = *(const bf16x8*)&Bs[(wn * 64 + ni * 16 + l15) * FPS + quad * 8];
        #pragma unroll
        for (int mi = 0; mi < 2; ++mi)
            #pragma unroll
            for (int ni = 0; ni < 4; ++ni)
                acc[mi][ni] = __builtin_amdgcn_mfma_f32_16x16x32_bf16(
                    af[mi], bf[ni], acc[mi][ni], 0, 0, 0);
        __syncthreads();
    }

    float bb[4];
    #pragma unroll
    for (int ni = 0; ni < 4; ++ni)
        bb[ni] = bias[c0 + wn * 64 + ni * 16 + l15];

    if (mode == 2) {
        u16* T = SH;                         // 64 x 72 u16
        const int b = r0 >> 11;
        const int n_base = r0 & (SEQN - 1);
        #pragma unroll
        for (int hh = 0; hh < 2; ++hh) {
            __syncthreads();
            if (wn == hh) {
                #pragma unroll
                for (int mi = 0; mi < 2; ++mi) {
                    const int rl = wm * 32 + mi * 16 + quad * 4;
                    int4 m4 = *(const int4*)&msk[b * SEQM + n_base + rl];
                    float mm[4];
                    mm[0] = m4.x ? 1.f : 0.f; mm[1] = m4.y ? 1.f : 0.f;
                    mm[2] = m4.z ? 1.f : 0.f; mm[3] = m4.w ? 1.f : 0.f;
                    #pragma unroll
                    for (int ni = 0; ni < 4; ++ni)
                        #pragma unroll
                        for (int r = 0; r < 4; ++r)
                            T[(rl + r) * 72 + ni * 16 + l15] =
                                f2bf((acc[mi][ni][r] + bb[ni]) * mm[r]);
                }
            }
            __syncthreads();
            const int d = tid >> 2, ms = (tid & 3) << 4;
            u16 tmp[16];
            #pragma unroll
            for (int j = 0; j < 16; ++j) tmp[j] = T[(ms + j) * 72 + d];
            const int hgl = (c0 >> 6) + hh;
            u16* dst = (u16*)Out + ((size_t)(b * NHEAD + hgl) * DHEAD + d) * SEQM
                       + n_base + ms;
            *(bf16x8*)&dst[0] = *(bf16x8*)&tmp[0];
            *(bf16x8*)&dst[8] = *(bf16x8*)&tmp[8];
        }
        return;
    }

    #pragma unroll
    for (int mi = 0; mi < 2; ++mi) {
        const int Rbase = r0 + wm * 32 + mi * 16 + quad * 4;
        const int b = Rbase >> 11;
        const int nb = Rbase & (SEQN - 1);
        #pragma unroll
        for (int ni = 0; ni < 4; ++ni) {
            const int C = c0 + wn * 64 + ni * 16 + l15;
            const int h = C >> 6, d = C & 63;
            if (mode == 0) {
                u16* ow = (u16*)Out;
                #pragma unroll
                for (int r = 0; r < 4; ++r)
                    ow[(((size_t)(b * NHEAD + h) * SEQN) + nb + r) * DHEAD + d] =
                        f2bf((acc[mi][ni][r] + bb[ni]) * QSCALE);
            } else if (mode == 1) {
                u16* ow = (u16*)Out;
                #pragma unroll
                for (int r = 0; r < 4; ++r)
                    ow[(((size_t)(b * NHEAD + h) * SEQN) + nb + r) * DHEAD + d] =
                        f2bf(acc[mi][ni][r] + bb[ni]);
            } else {
                float* ow = (float*)Out;
                #pragma unroll
                for (int r = 0; r < 4; ++r)
                    ow[(size_t)(Rbase + r) * DIMF + C] = acc[mi][ni][r] + bb[ni];
            }
        }
    }
}

// ---------------------------------------------------------------------------
// Flash unit (R13/R14's v7): 64-q block, 4 waves = 2 qg(32q) x 2 mh(32m),
// double-buffered DMA staging, XOR-swizzled LDS, XCD-swizzled bid decode,
// lean loop (exp2-folded q, inline mask8, l via mask-row MFMA), shuffle-free
// epilogue. LDS layout inside SH (u16): Ks dbuf [0,8192) | Vt dbuf
// [8192,16384) | Ps [16384,21504). Epilogue unions Osum/Lsum over Ks/Vt.
// ---------------------------------------------------------------------------
__device__ __forceinline__
void flash_unit(u16* __restrict__ SH,
                const u16* __restrict__ q, const u16* __restrict__ k,
                const u16* __restrict__ vt, const int* __restrict__ mask,
                u16* __restrict__ agg, int bid)
{
    u16* KsD  = SH;            // [2][4096]
    u16* VtsD = SH + 8192;     // [2][4096]
    u16* Ps   = SH + 16384;    // [4*32*FPS]
    float* Osum = (float*)SH;
    float* Lsum = (float*)(SH + 8192);

    const int tid  = threadIdx.x;
    const int wave = tid >> 6;
    const int lane = tid & 63;
    const int l15  = lane & 15;
    const int quad = lane >> 4;
    const int qg = wave >> 1, mh = wave & 1;

    const int xcd  = bid & 7, slot = bid >> 3;        // slot 0..63
    const int pair = (xcd << 1) | (slot & 1);         // (b*8+h) 0..15
    const int b = pair >> 3, h = pair & 7;
    const int n0 = (slot >> 1) * 64;

    const size_t hoff = (size_t)(b * NHEAD + h) * (size_t)SEQM * DHEAD;
    const u16* kb = k  + hoff;
    const u16* vb = vt + hoff;
    const int* mg = mask + b * SEQM;

    const int dr   = lane >> 3;
    const int doct = (lane & 7) ^ (dr & 7);
    const int g0 = wave, g1 = 4 + wave;
    const u16* kq0 = kb + (size_t)(g0 * 8 + dr) * DHEAD + doct * 8;
    const u16* kq1 = kb + (size_t)(g1 * 8 + dr) * DHEAD + doct * 8;
    const u16* vq0 = vb + (size_t)(g0 * 8 + dr) * SEQM + doct * 8;
    const u16* vq1 = vb + (size_t)(g1 * 8 + dr) * SEQM + doct * 8;

    bf16x8 qf[2][2];
    #pragma unroll
    for (int qh = 0; qh < 2; ++qh) {
        const u16* qp = q + hoff + (size_t)(n0 + qg * 32 + qh * 16 + l15) * DHEAD
                        + quad * 8;
        qf[qh][0] = *(const bf16x8*)qp;
        qf[qh][1] = *(const bf16x8*)(qp + 32);
    }

    load16(kq0, KsD + g0 * 512);
    load16(kq1, KsD + g1 * 512);
    load16(vq0, VtsD + g0 * 512);
    load16(vq1, VtsD + g1 * 512);
    bf16x8 mf_nxt = mask8(&mg[32 * mh + quad * 8]);

    f32x4 O[2][4] = {};
    f32x4 lacc[2] = {};
    u16* Pw = Ps + wave * (32 * FPS);
    const int xoct = l15 & 7;

    for (int mt = 0; mt < SEQM / 64; ++mt) {
        const int cur = mt & 1;
        __syncthreads();   // drains vmcnt -> tile mt resident; prior reads done
        bf16x8 mf = mf_nxt;
        if (mt + 1 < SEQM / 64) {
            const int m1 = (mt + 1) * 64;
            const int nb = cur ^ 1;
            load16(kq0 + (size_t)m1 * DHEAD, KsD + nb * 4096 + g0 * 512);
            load16(kq1 + (size_t)m1 * DHEAD, KsD + nb * 4096 + g1 * 512);
            load16(vq0 + m1, VtsD + nb * 4096 + g0 * 512);
            load16(vq1 + m1, VtsD + nb * 4096 + g1 * 512);
            mf_nxt = mask8(&mg[m1 + 32 * mh + quad * 8]);
        }
        const u16* Ks  = KsD + cur * 4096;
        const u16* Vts = VtsD + cur * 4096;

        f32x4 st[2][2] = {};
        #pragma unroll
        for (int sub = 0; sub < 2; ++sub) {
            const int mrow = 32 * mh + 16 * sub + l15;
            #pragma unroll
            for (int c = 0; c < 2; ++c) {
                const int oct = (4 * c + quad) ^ xoct;
                bf16x8 af = *(const bf16x8*)&Ks[mrow * 64 + oct * 8];
                #pragma unroll
                for (int qh = 0; qh < 2; ++qh)
                    st[qh][sub] = __builtin_amdgcn_mfma_f32_16x16x32_bf16(
                        af, qf[qh][c], st[qh][sub], 0, 0, 0);
            }
        }

        #pragma unroll
        for (int qh = 0; qh < 2; ++qh)
            #pragma unroll
            for (int sub = 0; sub < 2; ++sub) {
                ushort4 w4 = make_ushort4(
                    f2bf_fast(__builtin_amdgcn_exp2f(st[qh][sub][0])),
                    f2bf_fast(__builtin_amdgcn_exp2f(st[qh][sub][1])),
                    f2bf_fast(__builtin_amdgcn_exp2f(st[qh][sub][2])),
                    f2bf_fast(__builtin_amdgcn_exp2f(st[qh][sub][3])));
                *(ushort4*)&Pw[(qh * 16 + l15) * FPS + 16 * sub + 4 * quad] = w4;
            }

        bf16x8 vf[4];
        #pragma unroll
        for (int sd = 0; sd < 4; ++sd) {
            const int oct = (4 * mh + quad) ^ xoct;
            vf[sd] = *(const bf16x8*)&Vts[(16 * sd + l15) * 64 + oct * 8];
        }

        #pragma unroll
        for (int qh = 0; qh < 2; ++qh) {
            bf16x8 pf = *(const bf16x8*)&Pw[(qh * 16 + l15) * FPS + quad * 8];
            lacc[qh] = __builtin_amdgcn_mfma_f32_16x16x32_bf16(pf, mf, lacc[qh], 0, 0, 0);
            #pragma unroll
            for (int sd = 0; sd < 4; ++sd)
                O[qh][sd] = __builtin_amdgcn_mfma_f32_16x16x32_bf16(
                    pf, vf[sd], O[qh][sd], 0, 0, 0);
        }
    }

    __syncthreads();
    if (mh == 1) {
        #pragma unroll
        for (int qh = 0; qh < 2; ++qh) {
            #pragma unroll
            for (int sd = 0; sd < 4; ++sd)
                #pragma unroll
                for (int r = 0; r < 4; ++r)
                    Osum[qg * 2048 + (qh * 16 + quad * 4 + r) * 64 + 16 * sd + l15]
                        = O[qh][sd][r];
            if (l15 == 0) {
                #pragma unroll
                for (int r = 0; r < 4; ++r)
                    Lsum[qg * 32 + qh * 16 + quad * 4 + r] = lacc[qh][r];
            }
        }
    }
    __syncthreads();
    if (mh == 0) {
        #pragma unroll
        for (int qh = 0; qh < 2; ++qh)
            #pragma unroll
            for (int r = 0; r < 4; ++r) {
                const float inv = 1.f /
                    (lacc[qh][r] + Lsum[qg * 32 + qh * 16 + quad * 4 + r]);
                const int n = n0 + qg * 32 + qh * 16 + quad * 4 + r;
                u16* ag = agg + ((size_t)b * SEQN + n) * DIMF + h * DHEAD + l15;
                #pragma unroll
                for (int sd = 0; sd < 4; ++sd)
                    ag[16 * sd] = f2bf((O[qh][sd][r] +
                        Osum[qg * 2048 + (qh * 16 + quad * 4 + r) * 64 + 16 * sd + l15])
                        * inv);
            }
    }
}

// ---------------------------------------------------------------------------
// Persistent cooperative kernel: phases (weights cvt -> qkv -> flash -> out)
// separated by grid.sync(). Replaces 4 dispatches + 3 inter-dispatch gaps
// (~15-20 us of launch overhead, the largest remaining controllable cost).
// One 42 KB LDS union shared by all phases; 2 blocks/CU co-resident.
// ---------------------------------------------------------------------------
__global__ __launch_bounds__(256, 2)
void attn_fused(const float* __restrict__ x, const float* __restrict__ source,
                const int* __restrict__ mask,
                const float* __restrict__ Wq, const float* __restrict__ bq,
                const float* __restrict__ Wk, const float* __restrict__ bk,
                const float* __restrict__ Wv, const float* __restrict__ bv,
                const float* __restrict__ Wm, const float* __restrict__ bm,
                float* __restrict__ out,
                u16* __restrict__ qw, u16* __restrict__ kw,
                u16* __restrict__ vtw, u16* __restrict__ aggb,
                u16* __restrict__ wqb, u16* __restrict__ wkb,
                u16* __restrict__ wvb, u16* __restrict__ wmb)
{
    cg::grid_group grid = cg::this_grid();
    __shared__ __align__(16) u16 SH[21504];   // 42 KB, unioned across phases

    const int nblk = gridDim.x;

    // phase 0: weights fp32 -> bf16 (4 x 64K float4 groups, grid-stride)
    for (int i = blockIdx.x * 256 + threadIdx.x; i < 4 * 65536; i += nblk * 256) {
        const int w = i >> 16, j = (i & 65535) * 4;
        const float* in = (w == 0) ? Wq : (w == 1) ? Wk : (w == 2) ? Wv : Wm;
        u16* o = (w == 0) ? wqb : (w == 1) ? wkb : (w == 2) ? wvb : wmb;
        *(ushort4*)&o[j] = cvt4(*(const float4*)&in[j]);
    }
    grid.sync();

    // phase 1: qkv projections, 768 tiles grid-stride
    for (int t = blockIdx.x; t < 768; t += nblk) {
        const int bx = t & 63, by = (t >> 6) & 3, z = t >> 8;
        const float* X = (z == 0) ? x : source;
        const u16* W = (z == 0) ? wqb : (z == 1) ? wkb : wvb;
        const float* B = (z == 0) ? bq : (z == 1) ? bk : bv;
        void* O = (z == 0) ? (void*)qw : (z == 1) ? (void*)kw : (void*)vtw;
        gemm_tile(SH, X, nullptr, W, B, mask, O, z, bx, by);
        __syncthreads();   // SH reuse across tiles
    }
    grid.sync();

    // phase 2: flash attention, 512 units grid-stride
    for (int bid = blockIdx.x; bid < 512; bid += nblk) {
        flash_unit(SH, qw, kw, vtw, mask, aggb, bid);
        __syncthreads();
    }
    grid.sync();

    // phase 3: output projection, 256 tiles grid-stride
    for (int t = blockIdx.x; t < 256; t += nblk) {
        gemm_tile(SH, nullptr, aggb, wmb, bm, nullptr, (void*)out, 3,
                  t & 63, t >> 6);
        __syncthreads();
    }
}

extern "C" void kernel_launch(void* const* d_in, const int* in_sizes, int n_in,
                              void* d_out, int out_size, void* d_ws, size_t ws_size,
                              hipStream_t stream)
{
    (void)in_sizes; (void)n_in; (void)out_size; (void)ws_size;
    const float* x      = (const float*)d_in[0];
    const float* source = (const float*)d_in[1];
    const int*   mask   = (const int*)  d_in[2];
    const float* Wq = (const float*)d_in[3]; const float* bq = (const float*)d_in[4];
    const float* Wk = (const float*)d_in[5]; const float* bk = (const float*)d_in[6];
    const float* Wv = (const float*)d_in[7]; const float* bv = (const float*)d_in[8];
    const float* Wm = (const float*)d_in[9]; const float* bm = (const float*)d_in[10];
    float* out = (float*)d_out;

    const size_t SZ = (size_t)BATCH * SEQN * DIMF;   // 2,097,152 elems
    const size_t WZ = (size_t)DIMF * DIMF;
    u16* qw   = (u16*)d_ws;          // bf16 [B][H][n][d] (xQSCALE, +bq)
    u16* kw   = qw  + SZ;            // bf16 [B][H][m][d]
    u16* vtw  = kw  + SZ;            // bf16 V^T [B][H][d][m], masked
    u16* aggb = vtw + SZ;            // bf16 [B][n][H*64+d]
    u16* wqb  = aggb + SZ;
    u16* wkb  = wqb + WZ;
    u16* wvb  = wkb + WZ;
    u16* wmb  = wvb + WZ;            // ~18.9 MB total

    // co-residency: grid = min(512, occupancy * 256), grid-stride loops adapt
    int bpc = 0;
    hipOccupancyMaxActiveBlocksPerMultiprocessor(&bpc, attn_fused, 256, 0);
    if (bpc < 1) bpc = 1;
    int nblk = bpc * 256;
    if (nblk > 512) nblk = 512;

    void* args[] = {
        (void*)&x, (void*)&source, (void*)&mask,
        (void*)&Wq, (void*)&bq, (void*)&Wk, (void*)&bk,
        (void*)&Wv, (void*)&bv, (void*)&Wm, (void*)&bm,
        (void*)&out,
        (void*)&qw, (void*)&kw, (void*)&vtw, (void*)&aggb,
        (void*)&wqb, (void*)&wkb, (void*)&wvb, (void*)&wmb
    };
    hipLaunchCooperativeKernel(attn_fused, dim3(nblk), dim3(256),
                               args, 0, stream);
}

// Round 16
// 148.435 us; speedup vs baseline: 1.9515x; 1.9515x over previous
//
#include <hip/hip_runtime.h>
#include <hip/hip_bf16.h>

#define DIMF 512
#define NHEAD 8
#define DHEAD 64
#define BATCH 2
#define SEQN 2048
#define SEQM 2048
#define FPS 40        // padded LDS row stride (u16): 32 data + 8 pad -> 2-way banks
#define QSCALE 0.18033688011112042f   // 0.125 * log2(e)

typedef unsigned short u16;
typedef __attribute__((ext_vector_type(8))) short bf16x8;
typedef __attribute__((ext_vector_type(4))) float f32x4;

static __device__ __forceinline__ u16 f2bf(float f) {
    unsigned u = __float_as_uint(f);
    u += 0x7FFF + ((u >> 16) & 1);      // RNE
    return (u16)(u >> 16);
}
static __device__ __forceinline__ u16 f2bf_fast(float f) {
    return (u16)((__float_as_uint(f) + 0x8000u) >> 16);
}

static __device__ __forceinline__
void load16(const u16* g, u16* l) {
    __builtin_amdgcn_global_load_lds(
        (const __attribute__((address_space(1))) void*)g,
        (__attribute__((address_space(3))) void*)l,
        16, 0, 0);
}

// ---------------------------------------------------------------------------
// weights fp32 -> bf16 (+ mask int -> bf16 {0,1})
// ---------------------------------------------------------------------------
__global__ __launch_bounds__(256)
void cvt_w(const float* __restrict__ wq, const float* __restrict__ wk,
           const float* __restrict__ wv, const float* __restrict__ wm,
           const int* __restrict__ mask,
           u16* __restrict__ wqb, u16* __restrict__ wkb,
           u16* __restrict__ wvb, u16* __restrict__ wmb,
           u16* __restrict__ maskbf)
{
    int i = (blockIdx.x * 256 + threadIdx.x) * 4;
    if (blockIdx.y == 4) {
        if (i < BATCH * SEQM) {
            int4 m4 = *(const int4*)&mask[i];
            *(ushort4*)&maskbf[i] = make_ushort4(m4.x ? 0x3F80 : 0, m4.y ? 0x3F80 : 0,
                                                 m4.z ? 0x3F80 : 0, m4.w ? 0x3F80 : 0);
        }
        return;
    }
    const float* in = (blockIdx.y == 0) ? wq : (blockIdx.y == 1) ? wk
                    : (blockIdx.y == 2) ? wv : wm;
    u16* out = (blockIdx.y == 0) ? wqb : (blockIdx.y == 1) ? wkb
             : (blockIdx.y == 2) ? wvb : wmb;
    if (i >= DIMF * DIMF) return;
    float4 v = *(const float4*)&in[i];
    *(ushort4*)&out[i] = make_ushort4(f2bf(v.x), f2bf(v.y), f2bf(v.z), f2bf(v.w));
}

// ---------------------------------------------------------------------------
// bf16 MFMA GEMM v2: double-buffered, ONE barrier per K-step.
// iter kt: stage regs(kt+1) -> buf[kt+1 & 1]; issue loads(kt+2); compute
// buf[kt & 1]; barrier. Loads ride ~2 iterations before consumption.
// LDS buffer bases computed by offset (no LDS-pointer arrays).
// 64x128 tile, 4 waves (2x2), wave 32x64 = 2x4 frags. A from fp32 (fused
// cvt) or bf16. Padded LDS stride 40 u16 (2-way banks).
// mode 0: q -> bf16 [B][H][n][d], (val+bias)*QSCALE (softmax+exp2 folded)
// mode 1: k -> bf16 [B][H][m][d]
// mode 2: V^T -> bf16 [B][H][d][m], masked rows zeroed, transposed in-block
// mode 3: fp32 row-major [4096][512]
// ---------------------------------------------------------------------------
#define ASZ (64 * FPS)
#define BSZ (128 * FPS)

__device__ __forceinline__
void gemm_mfma(const float* __restrict__ Xf, const u16* __restrict__ Xb,
               const u16* __restrict__ W, const float* __restrict__ bias,
               const int* __restrict__ msk, void* __restrict__ Out, int mode)
{
    __shared__ __align__(16) u16 SH[2 * ASZ + 2 * BSZ];   // 30 KB

    const int tid  = threadIdx.x;
    const int wave = tid >> 6;
    const int lane = tid & 63;
    const int l15  = lane & 15;
    const int quad = lane >> 4;
    const int wm = wave & 1, wn = wave >> 1;
    const int r0 = blockIdx.x * 64, c0 = blockIdx.y * 128;

    f32x4 acc[2][4] = {};

    const int br = tid >> 2, boct = tid & 3;        // B: rows br, br+64
    const int ar = tid >> 3, aseg = tid & 7;        // A fp32: rows ar, ar+32

    bf16x8 rb0, rb1, rab;
    float4 ra0, ra1;

    auto loadg = [&](int k0) {
        rb0 = *(const bf16x8*)&W[(size_t)(c0 + br) * DIMF + k0 + boct * 8];
        rb1 = *(const bf16x8*)&W[(size_t)(c0 + br + 64) * DIMF + k0 + boct * 8];
        if (Xf) {
            ra0 = *(const float4*)&Xf[(size_t)(r0 + ar) * DIMF + k0 + aseg * 4];
            ra1 = *(const float4*)&Xf[(size_t)(r0 + ar + 32) * DIMF + k0 + aseg * 4];
        } else {
            rab = *(const bf16x8*)&Xb[(size_t)(r0 + br) * DIMF + k0 + boct * 8];
        }
    };
    auto stage = [&](int buf) {
        u16* As = SH + buf * ASZ;
        u16* Bs = SH + 2 * ASZ + buf * BSZ;
        if (Xf) {
            *(ushort4*)&As[ar * FPS + aseg * 4] =
                make_ushort4(f2bf(ra0.x), f2bf(ra0.y), f2bf(ra0.z), f2bf(ra0.w));
            *(ushort4*)&As[(ar + 32) * FPS + aseg * 4] =
                make_ushort4(f2bf(ra1.x), f2bf(ra1.y), f2bf(ra1.z), f2bf(ra1.w));
        } else {
            *(bf16x8*)&As[br * FPS + boct * 8] = rab;
        }
        *(bf16x8*)&Bs[br * FPS + boct * 8] = rb0;
        *(bf16x8*)&Bs[(br + 64) * FPS + boct * 8] = rb1;
    };

    loadg(0);
    stage(0);
    loadg(32);
    __syncthreads();

    const int NK = DIMF / 32;   // 16
    for (int kt = 0; kt < NK; ++kt) {
        const int cur = kt & 1;
        if (kt + 1 < NK) stage(cur ^ 1);       // regs for kt+1 (vmcnt hidden 1 iter)
        if (kt + 2 < NK) loadg((kt + 2) * 32); // in flight through this compute
        const u16* As = SH + cur * ASZ;
        const u16* Bs = SH + 2 * ASZ + cur * BSZ;

        bf16x8 af[2], bf[4];
        #pragma unroll
        for (int mi = 0; mi < 2; ++mi)
            af[mi] = *(const bf16x8*)&As[(wm * 32 + mi * 16 + l15) * FPS + quad * 8];
        #pragma unroll
        for (int ni = 0; ni < 4; ++ni)
            bf[ni] = *(const bf16x8*)&Bs[(wn * 64 + ni * 16 + l15) * FPS + quad * 8];
        #pragma unroll
        for (int mi = 0; mi < 2; ++mi)
            #pragma unroll
            for (int ni = 0; ni < 4; ++ni)
                acc[mi][ni] = __builtin_amdgcn_mfma_f32_16x16x32_bf16(
                    af[mi], bf[ni], acc[mi][ni], 0, 0, 0);
        __syncthreads();   // one barrier/iter: buf[cur] reads done, buf[cur^1] full
    }

    float bb[4];
    #pragma unroll
    for (int ni = 0; ni < 4; ++ni)
        bb[ni] = bias[c0 + wn * 64 + ni * 16 + l15];

    if (mode == 2) {
        u16* T = SH;                         // 64 x 72 u16 (9 KB of 30)
        const int b = r0 >> 11;
        const int n_base = r0 & (SEQN - 1);
        #pragma unroll
        for (int hh = 0; hh < 2; ++hh) {
            __syncthreads();
            if (wn == hh) {
                #pragma unroll
                for (int mi = 0; mi < 2; ++mi) {
                    const int rl = wm * 32 + mi * 16 + quad * 4;
                    int4 m4 = *(const int4*)&msk[b * SEQM + n_base + rl];
                    float mm[4];
                    mm[0] = m4.x ? 1.f : 0.f; mm[1] = m4.y ? 1.f : 0.f;
                    mm[2] = m4.z ? 1.f : 0.f; mm[3] = m4.w ? 1.f : 0.f;
                    #pragma unroll
                    for (int ni = 0; ni < 4; ++ni)
                        #pragma unroll
                        for (int r = 0; r < 4; ++r)
                            T[(rl + r) * 72 + ni * 16 + l15] =
                                f2bf((acc[mi][ni][r] + bb[ni]) * mm[r]);
                }
            }
            __syncthreads();
            const int d = tid >> 2, ms = (tid & 3) << 4;
            u16 tmp[16];
            #pragma unroll
            for (int j = 0; j < 16; ++j) tmp[j] = T[(ms + j) * 72 + d];
            const int hgl = (c0 >> 6) + hh;
            u16* dst = (u16*)Out + ((size_t)(b * NHEAD + hgl) * DHEAD + d) * SEQM
                       + n_base + ms;
            *(bf16x8*)&dst[0] = *(bf16x8*)&tmp[0];
            *(bf16x8*)&dst[8] = *(bf16x8*)&tmp[8];
        }
        return;
    }

    #pragma unroll
    for (int mi = 0; mi < 2; ++mi) {
        const int Rbase = r0 + wm * 32 + mi * 16 + quad * 4;   // +r, r=0..3
        const int b = Rbase >> 11;
        const int nb = Rbase & (SEQN - 1);
        #pragma unroll
        for (int ni = 0; ni < 4; ++ni) {
            const int C = c0 + wn * 64 + ni * 16 + l15;
            const int h = C >> 6, d = C & 63;
            if (mode == 0) {
                u16* ow = (u16*)Out;
                #pragma unroll
                for (int r = 0; r < 4; ++r)
                    ow[(((size_t)(b * NHEAD + h) * SEQN) + nb + r) * DHEAD + d] =
                        f2bf((acc[mi][ni][r] + bb[ni]) * QSCALE);
            } else if (mode == 1) {
                u16* ow = (u16*)Out;
                #pragma unroll
                for (int r = 0; r < 4; ++r)
                    ow[(((size_t)(b * NHEAD + h) * SEQN) + nb + r) * DHEAD + d] =
                        f2bf(acc[mi][ni][r] + bb[ni]);
            } else {
                float* ow = (float*)Out;
                #pragma unroll
                for (int r = 0; r < 4; ++r)
                    ow[(size_t)(Rbase + r) * DIMF + C] = acc[mi][ni][r] + bb[ni];
            }
        }
    }
}

__global__ __launch_bounds__(256, 3)
void qkv_proj(const float* __restrict__ x, const float* __restrict__ src,
              const u16* __restrict__ wqb, const float* __restrict__ bq,
              const u16* __restrict__ wkb, const float* __restrict__ bk,
              const u16* __restrict__ wvb, const float* __restrict__ bv,
              const int* __restrict__ mask,
              u16* __restrict__ qw, u16* __restrict__ kw, u16* __restrict__ vtw)
{
    const int z = blockIdx.z;
    const float* X = (z == 0) ? x : src;
    const u16* W = (z == 0) ? wqb : (z == 1) ? wkb : wvb;
    const float* B = (z == 0) ? bq : (z == 1) ? bk : bv;
    void* O = (z == 0) ? (void*)qw : (z == 1) ? (void*)kw : (void*)vtw;
    gemm_mfma(X, nullptr, W, B, mask, O, z);
}

__global__ __launch_bounds__(256, 3)
void out_proj(const u16* __restrict__ aggb, const u16* __restrict__ wmb,
              const float* __restrict__ bm, float* __restrict__ out)
{
    gemm_mfma(nullptr, aggb, wmb, bm, nullptr, (void*)out, 3);
}

// ---------------------------------------------------------------------------
// MFMA flash attention v5 (R11's best-measured): double-buffered DMA staging,
// XCD-swizzled grid, XOR-swizzled LDS, lean loop (exp2-folded q, mask-free,
// l via mask-row MFMA), shuffle-free epilogue.
// Block = 64 q-rows; 4 waves = 2 qg(32q) x 2 mh(32m); grid 512.
// ---------------------------------------------------------------------------
__global__ __launch_bounds__(256, 2)
void flash_attn_mfma(const u16* __restrict__ q, const u16* __restrict__ k,
                     const u16* __restrict__ vt, const u16* __restrict__ maskbf,
                     u16* __restrict__ agg)
{
    __shared__ __align__(16) u16 KsD[2][4096];    // 16 KB
    __shared__ __align__(16) u16 VtsD[2][4096];   // 16 KB
    __shared__ u16 Ps[4 * 32 * FPS];              // 10 KB
    float* Osum = (float*)&KsD[0][0];             // epilogue union: [qg][32][64]
    float* Lsum = (float*)&VtsD[0][0];            // [qg][32]

    const int tid  = threadIdx.x;
    const int wave = tid >> 6;
    const int lane = tid & 63;
    const int l15  = lane & 15;
    const int quad = lane >> 4;
    const int qg = wave >> 1, mh = wave & 1;

    // XCD swizzle: bid&7 = XCD (dispatch round-robins blocks over 8 XCDs)
    const int bid  = blockIdx.x;
    const int xcd  = bid & 7, slot = bid >> 3;        // slot 0..63
    const int pair = (xcd << 1) | (slot & 1);         // (b*8+h) 0..15
    const int b = pair >> 3, h = pair & 7;
    const int n0 = (slot >> 1) * 64;

    const size_t hoff = (size_t)(b * NHEAD + h) * (size_t)SEQM * DHEAD;
    const u16* kb = k  + hoff;
    const u16* vb = vt + hoff;
    const u16* mb = maskbf + b * SEQM;

    // DMA geometry: group g covers rows 8g..8g+7; lane l -> row 8g+(l>>3),
    // source oct = (l&7)^((l>>3)&7), stored lane-contiguously (XOR swizzle).
    const int dr   = lane >> 3;
    const int doct = (lane & 7) ^ (dr & 7);
    const int g0 = wave, g1 = 4 + wave;
    const u16* kq0 = kb + (size_t)(g0 * 8 + dr) * DHEAD + doct * 8;
    const u16* kq1 = kb + (size_t)(g1 * 8 + dr) * DHEAD + doct * 8;
    const u16* vq0 = vb + (size_t)(g0 * 8 + dr) * SEQM + doct * 8;
    const u16* vq1 = vb + (size_t)(g1 * 8 + dr) * SEQM + doct * 8;

    // Q B-frags (prescaled by 0.125*log2e): cols q = n0 + qg*32 + qh*16 + l15
    bf16x8 qf[2][2];
    #pragma unroll
    for (int qh = 0; qh < 2; ++qh) {
        const u16* qp = q + hoff + (size_t)(n0 + qg * 32 + qh * 16 + l15) * DHEAD
                        + quad * 8;
        qf[qh][0] = *(const bf16x8*)qp;
        qf[qh][1] = *(const bf16x8*)(qp + 32);
    }

    // prologue: tile 0 -> buffer 0; mask frag 0 -> register
    load16(kq0, &KsD[0][g0 * 512]);
    load16(kq1, &KsD[0][g1 * 512]);
    load16(vq0, &VtsD[0][g0 * 512]);
    load16(vq1, &VtsD[0][g1 * 512]);
    bf16x8 mf_nxt = *(const bf16x8*)&mb[32 * mh + quad * 8];

    f32x4 O[2][4] = {};    // [qh][sd]: row q = quad*4+r, col d = 16*sd+l15
    f32x4 lacc[2] = {};
    u16* Pw = Ps + wave * (32 * FPS);
    const int xoct = l15 & 7;

    for (int mt = 0; mt < SEQM / 64; ++mt) {
        const int cur = mt & 1;
        __syncthreads();   // drains vmcnt -> tile mt resident; prior reads done
        bf16x8 mf = mf_nxt;
        if (mt + 1 < SEQM / 64) {
            const int m1 = (mt + 1) * 64;
            const int nb = cur ^ 1;
            load16(kq0 + (size_t)m1 * DHEAD, &KsD[nb][g0 * 512]);
            load16(kq1 + (size_t)m1 * DHEAD, &KsD[nb][g1 * 512]);
            load16(vq0 + m1, &VtsD[nb][g0 * 512]);
            load16(vq1 + m1, &VtsD[nb][g1 * 512]);
            mf_nxt = *(const bf16x8*)&mb[m1 + 32 * mh + quad * 8];
        }
        const u16* Ks  = KsD[cur];
        const u16* Vts = VtsD[cur];

        // S^T (this wave's 32-m half): rows m, cols q; af shared across qh
        f32x4 st[2][2] = {};
        #pragma unroll
        for (int sub = 0; sub < 2; ++sub) {
            const int mrow = 32 * mh + 16 * sub + l15;
            #pragma unroll
            for (int c = 0; c < 2; ++c) {
                const int oct = (4 * c + quad) ^ xoct;
                bf16x8 af = *(const bf16x8*)&Ks[mrow * 64 + oct * 8];
                #pragma unroll
                for (int qh = 0; qh < 2; ++qh)
                    st[qh][sub] = __builtin_amdgcn_mfma_f32_16x16x32_bf16(
                        af, qf[qh][c], st[qh][sub], 0, 0, 0);
            }
        }

        // p = 2^s, pack, P^T -> wave-private LDS (lgkm-ordered, no barrier)
        #pragma unroll
        for (int qh = 0; qh < 2; ++qh)
            #pragma unroll
            for (int sub = 0; sub < 2; ++sub) {
                ushort4 w4 = make_ushort4(
                    f2bf_fast(__builtin_amdgcn_exp2f(st[qh][sub][0])),
                    f2bf_fast(__builtin_amdgcn_exp2f(st[qh][sub][1])),
                    f2bf_fast(__builtin_amdgcn_exp2f(st[qh][sub][2])),
                    f2bf_fast(__builtin_amdgcn_exp2f(st[qh][sub][3])));
                *(ushort4*)&Pw[(qh * 16 + l15) * FPS + 16 * sub + 4 * quad] = w4;
            }

        // V frags shared across qh
        bf16x8 vf[4];
        #pragma unroll
        for (int sd = 0; sd < 4; ++sd) {
            const int oct = (4 * mh + quad) ^ xoct;
            vf[sd] = *(const bf16x8*)&Vts[(16 * sd + l15) * 64 + oct * 8];
        }

        #pragma unroll
        for (int qh = 0; qh < 2; ++qh) {
            bf16x8 pf = *(const bf16x8*)&Pw[(qh * 16 + l15) * FPS + quad * 8];
            lacc[qh] = __builtin_amdgcn_mfma_f32_16x16x32_bf16(pf, mf, lacc[qh], 0, 0, 0);
            #pragma unroll
            for (int sd = 0; sd < 4; ++sd)
                O[qh][sd] = __builtin_amdgcn_mfma_f32_16x16x32_bf16(
                    pf, vf[sd], O[qh][sd], 0, 0, 0);
        }
    }

    // combine m-halves per q-group (LDS unioned over dead Ks/Vts)
    __syncthreads();
    if (mh == 1) {
        #pragma unroll
        for (int qh = 0; qh < 2; ++qh) {
            #pragma unroll
            for (int sd = 0; sd < 4; ++sd)
                #pragma unroll
                for (int r = 0; r < 4; ++r)
                    Osum[qg * 2048 + (qh * 16 + quad * 4 + r) * 64 + 16 * sd + l15]
                        = O[qh][sd][r];
            if (l15 == 0) {
                #pragma unroll
                for (int r = 0; r < 4; ++r)
                    Lsum[qg * 32 + qh * 16 + quad * 4 + r] = lacc[qh][r];
            }
        }
    }
    __syncthreads();
    if (mh == 0) {
        #pragma unroll
        for (int qh = 0; qh < 2; ++qh)
            #pragma unroll
            for (int r = 0; r < 4; ++r) {
                const float inv = 1.f /
                    (lacc[qh][r] + Lsum[qg * 32 + qh * 16 + quad * 4 + r]);
                const int n = n0 + qg * 32 + qh * 16 + quad * 4 + r;
                u16* ag = agg + ((size_t)b * SEQN + n) * DIMF + h * DHEAD + l15;
                #pragma unroll
                for (int sd = 0; sd < 4; ++sd)
                    ag[16 * sd] = f2bf((O[qh][sd][r] +
                        Osum[qg * 2048 + (qh * 16 + quad * 4 + r) * 64 + 16 * sd + l15])
                        * inv);
            }
    }
}

extern "C" void kernel_launch(void* const* d_in, const int* in_sizes, int n_in,
                              void* d_out, int out_size, void* d_ws, size_t ws_size,
                              hipStream_t stream)
{
    (void)in_sizes; (void)n_in; (void)out_size; (void)ws_size;
    const float* x      = (const float*)d_in[0];
    const float* source = (const float*)d_in[1];
    const int*   mask   = (const int*)  d_in[2];
    const float* Wq = (const float*)d_in[3]; const float* bq = (const float*)d_in[4];
    const float* Wk = (const float*)d_in[5]; const float* bk = (const float*)d_in[6];
    const float* Wv = (const float*)d_in[7]; const float* bv = (const float*)d_in[8];
    const float* Wm = (const float*)d_in[9]; const float* bm = (const float*)d_in[10];
    float* out = (float*)d_out;

    const size_t SZ = (size_t)BATCH * SEQN * DIMF;   // 2,097,152 elems
    const size_t WZ = (size_t)DIMF * DIMF;
    u16* qw   = (u16*)d_ws;          // bf16 [B][H][n][d] (xQSCALE, +bq)
    u16* kw   = qw  + SZ;            // bf16 [B][H][m][d]
    u16* vtw  = kw  + SZ;            // bf16 V^T [B][H][d][m], masked
    u16* aggb = vtw + SZ;            // bf16 [B][n][H*64+d]
    u16* wqb  = aggb + SZ;
    u16* wkb  = wqb + WZ;
    u16* wvb  = wkb + WZ;
    u16* wmb  = wvb + WZ;
    u16* maskbf = wmb + WZ;          // bf16 [B][M] {0,1}; ~19 MB total

    dim3 gcvt((WZ / 4 + 255) / 256, 5);
    cvt_w<<<gcvt, 256, 0, stream>>>(Wq, Wk, Wv, Wm, mask,
                                    wqb, wkb, wvb, wmb, maskbf);

    dim3 gproj(4096 / 64, 512 / 128, 3);    // 768 blocks
    qkv_proj<<<gproj, 256, 0, stream>>>(x, source, wqb, bq, wkb, bk, wvb, bv,
                                        mask, qw, kw, vtw);

    flash_attn_mfma<<<512, 256, 0, stream>>>(qw, kw, vtw, maskbf, aggb);

    dim3 gout(4096 / 64, 512 / 128);        // 256 blocks
    out_proj<<<gout, 256, 0, stream>>>(aggb, wmb, bm, out);
}